// Round 5
// baseline (239.473 us; speedup 1.0000x reference)
//
#include <hip/hip_runtime.h>
#include <hip/hip_bf16.h>
#include <stdint.h>

typedef __bf16 bf16_t;
typedef bf16_t bf16x8 __attribute__((ext_vector_type(8)));
typedef float f32x4 __attribute__((ext_vector_type(4)));

#define NN 10000

__device__ __forceinline__ float b2f(unsigned short u) {
  union { unsigned int i; float f; } c; c.i = ((unsigned int)u) << 16; return c.f;
}
__device__ __forceinline__ unsigned short f2b(float f) {
  union { float f; unsigned int i; } c; c.f = f;
  unsigned int x = c.i;
  x += 0x7FFFu + ((x >> 16) & 1u);
  return (unsigned short)(x >> 16);
}

// async 16B global->LDS (m97 pattern)
__device__ __forceinline__ void load_lds16(const void* g, void* l) {
  __builtin_amdgcn_global_load_lds(
      (const __attribute__((address_space(1))) unsigned int*)g,
      (__attribute__((address_space(3))) unsigned int*)l, 16, 0, 0);
}

// ---------------- prep: x->bf16 + edge degree ----------------
__global__ void prep(const float* __restrict__ x, const int* __restrict__ dst,
                     int* __restrict__ edeg, unsigned short* __restrict__ xb, int E) {
  int t = blockIdx.x * 256 + threadIdx.x;
  const int XN = NN * 512;
  if (t < XN) { xb[t] = f2b(x[t]); return; }
  t -= XN;
  if (t < E) atomicAdd(&edeg[dst[t]], 1);
}

// ---------------- LDS-tiled transpose: W[512][*] fp32 -> Wt[*][512] bf16 ----------------
// z=0: W1 (512 cols), z=1: W2 (512 cols), z=2: Wc (100 cols -> padded 128 rows out)
__global__ __launch_bounds__(256)
void wtrans(const float* __restrict__ W1, const float* __restrict__ W2,
            const float* __restrict__ Wc,
            unsigned short* __restrict__ W1t, unsigned short* __restrict__ W2t,
            unsigned short* __restrict__ Wct) {
  __shared__ float tile[64][65];
  const int z = blockIdx.z;
  const float* W = (z == 0) ? W1 : (z == 1) ? W2 : Wc;
  unsigned short* Wt = (z == 0) ? W1t : (z == 1) ? W2t : Wct;
  const int ncols = (z == 2) ? 100 : 512;
  if (z == 2 && blockIdx.y >= 2) return;
  const int tr0 = blockIdx.x * 64;   // k-block
  const int tc0 = blockIdx.y * 64;   // n-block
  const int t = threadIdx.x;
  const int r = t >> 2, c4 = t & 3;  // r: 0..63 rows, c4: 4 float4-chunks of 16 floats
  #pragma unroll
  for (int i = 0; i < 4; i++) {
    int col = c4 * 16 + i * 4;       // 0..63 step 4
    float4 v;
    int gc = tc0 + col;
    if (gc + 3 < ncols) {
      v = *(const float4*)&W[(size_t)(tr0 + r) * ncols + gc];
    } else {
      v.x = (gc + 0 < ncols) ? W[(size_t)(tr0 + r) * ncols + gc + 0] : 0.f;
      v.y = (gc + 1 < ncols) ? W[(size_t)(tr0 + r) * ncols + gc + 1] : 0.f;
      v.z = (gc + 2 < ncols) ? W[(size_t)(tr0 + r) * ncols + gc + 2] : 0.f;
      v.w = (gc + 3 < ncols) ? W[(size_t)(tr0 + r) * ncols + gc + 3] : 0.f;
    }
    tile[r][col] = v.x; tile[r][col + 1] = v.y;
    tile[r][col + 2] = v.z; tile[r][col + 3] = v.w;
  }
  __syncthreads();
  // write out: out-row o = original col (tc0+o), 64 k-elems from tile[.][o]
  const int o = t >> 2;              // 0..63
  #pragma unroll
  for (int i = 0; i < 4; i++) {
    int k = c4 * 16 + i * 4;
    ushort4 u;
    u.x = f2b(tile[k + 0][o]); u.y = f2b(tile[k + 1][o]);
    u.z = f2b(tile[k + 2][o]); u.w = f2b(tile[k + 3][o]);
    *(ushort4*)&Wt[(size_t)(tc0 + o) * 512 + tr0 + k] = u;
  }
}

// single-block: exclusive scan edeg -> rowstart, dinv = rsqrt(1+deg), edeg -> 0 (fill cursor)
__global__ void csr_scan(int* __restrict__ edeg, int* __restrict__ rowstart,
                         float* __restrict__ dinv, int n) {
  __shared__ int partial[256];
  const int t = threadIdx.x;
  const int per = (n + 255) / 256;
  const int lo = t * per;
  const int hi = (lo + per < n) ? lo + per : n;
  int s = 0;
  for (int i = lo; i < hi; i++) s += edeg[i];
  partial[t] = s;
  __syncthreads();
  for (int off = 1; off < 256; off <<= 1) {
    int v = (t >= off) ? partial[t - off] : 0;
    __syncthreads();
    partial[t] += v;
    __syncthreads();
  }
  int run = (t > 0) ? partial[t - 1] : 0;
  for (int i = lo; i < hi; i++) {
    int d = edeg[i];
    rowstart[i] = run; run += d;
    dinv[i] = rsqrtf(1.0f + (float)d);
    edeg[i] = 0;
  }
  if (t == 255) rowstart[n] = run;
}

__global__ void csr_fill(const int* __restrict__ src, const int* __restrict__ dst,
                         const float* __restrict__ dinv, const int* __restrict__ rowstart,
                         int* __restrict__ cursor, int* __restrict__ csr_src,
                         float* __restrict__ csr_norm, int E) {
  int e = blockIdx.x * 256 + threadIdx.x;
  if (e >= E) return;
  int s = src[e], d = dst[e];
  int pos = rowstart[d] + atomicAdd(&cursor[d], 1);
  csr_src[pos] = s;
  csr_norm[pos] = dinv[s] * dinv[d];
}

// ---- GEMM: C[M][N] = A[M][512](bf16) * Bt[N][512]^T(bf16); dbuf-pipelined K-loop ----
__device__ __forceinline__ f32x4 mfma16(bf16x8 a, bf16x8 b, f32x4 c) {
  return __builtin_amdgcn_mfma_f32_16x16x32_bf16(a, b, c, 0, 0, 0);
}

template <bool BIAS, bool OBF16>
__global__ __launch_bounds__(256)
void gemm_bb(const unsigned short* __restrict__ A, const unsigned short* __restrict__ Bt,
             void* __restrict__ Cv, const float* __restrict__ bias,
             int M, int Ncols, int ldc)
{
  // 2 buffers x (128x32 A + 128x32 B) bf16 = 32 KB
  __shared__ __align__(16) unsigned short As[2][128 * 32];
  __shared__ __align__(16) unsigned short Bs[2][128 * 32];
  const int tid = threadIdx.x;
  const int lane = tid & 63;
  const int wm = (tid >> 6) >> 1;
  const int wn = (tid >> 6) & 1;
  const int tm = blockIdx.x, tn = blockIdx.y;
  const int quad = lane >> 4, l15 = lane & 15;

  // staging map: thread tid -> LDS byte offset tid*16 within buffer (wave-contiguous)
  const int r0 = tid >> 2, kc = tid & 3;
  int ga0 = tm * 128 + r0;       if (ga0 > M - 1) ga0 = M - 1;
  int ga1 = tm * 128 + 64 + r0;  if (ga1 > M - 1) ga1 = M - 1;
  const int gb0 = tn * 128 + r0;
  const int gb1 = tn * 128 + 64 + r0;
  const unsigned short* gA0 = A + (size_t)ga0 * 512 + kc * 8;
  const unsigned short* gA1 = A + (size_t)ga1 * 512 + kc * 8;
  const unsigned short* gB0 = Bt + (size_t)gb0 * 512 + kc * 8;
  const unsigned short* gB1 = Bt + (size_t)gb1 * 512 + kc * 8;
  const int loff0 = r0 * 32 + kc * 8;
  const int loff1 = (64 + r0) * 32 + kc * 8;

  f32x4 acc[4][4];
  #pragma unroll
  for (int i = 0; i < 4; i++)
    #pragma unroll
    for (int j = 0; j < 4; j++) {
      f32x4 z = {0.f, 0.f, 0.f, 0.f};
      acc[i][j] = z;
    }

  // prologue: stage k0=0 into buffer 0
  load_lds16(gA0, &As[0][loff0]);
  load_lds16(gA1, &As[0][loff1]);
  load_lds16(gB0, &Bs[0][loff0]);
  load_lds16(gB1, &Bs[0][loff1]);
  __syncthreads();   // compiler drains vmcnt before barrier -> buf0 ready

  for (int it = 0; it < 16; ++it) {
    const int cur = it & 1;
    if (it < 15) {
      const int k1 = (it + 1) * 32;
      const int nxt = cur ^ 1;
      load_lds16(gA0 + k1, &As[nxt][loff0]);   // async, in flight during MFMA below
      load_lds16(gA1 + k1, &As[nxt][loff1]);
      load_lds16(gB0 + k1, &Bs[nxt][loff0]);
      load_lds16(gB1 + k1, &Bs[nxt][loff1]);
    }
    bf16x8 af[4], bfr[4];
    #pragma unroll
    for (int i = 0; i < 4; i++) {
      af[i]  = *(const bf16x8*)&As[cur][(wm * 64 + i * 16 + l15) * 32 + quad * 8];
      bfr[i] = *(const bf16x8*)&Bs[cur][(wn * 64 + i * 16 + l15) * 32 + quad * 8];
    }
    #pragma unroll
    for (int i = 0; i < 4; i++)
      #pragma unroll
      for (int j = 0; j < 4; j++)
        acc[i][j] = mfma16(af[i], bfr[j], acc[i][j]);
    __syncthreads();   // waits own vmcnt (prefetch) + lgkm (ds_reads), then barrier
  }

  // epilogue: C/D layout col=lane&15, row=quad*4+reg  [m89-verified]
  #pragma unroll
  for (int i = 0; i < 4; i++) {
    const int row_base = tm * 128 + wm * 64 + i * 16 + quad * 4;
    #pragma unroll
    for (int j = 0; j < 4; j++) {
      const int col = tn * 128 + wn * 64 + j * 16 + l15;
      if (col < Ncols) {
        float badd = BIAS ? bias[col] : 0.f;
        #pragma unroll
        for (int r = 0; r < 4; r++) {
          int row = row_base + r;
          if (row < M) {
            float v = acc[i][j][r] + badd;
            if (OBF16) ((unsigned short*)Cv)[(size_t)row * ldc + col] = f2b(v);
            else       ((float*)Cv)[(size_t)row * ldc + col] = v;
          }
        }
      }
    }
  }
}

// ------ gather aggregation (bf16 rows): one wave per dst node, 8-edge unroll ------
__device__ __forceinline__ void acc8(float* a, uint4 v, float nm) {
  a[0] = fmaf(b2f((unsigned short)(v.x & 0xffffu)), nm, a[0]);
  a[1] = fmaf(b2f((unsigned short)(v.x >> 16)),     nm, a[1]);
  a[2] = fmaf(b2f((unsigned short)(v.y & 0xffffu)), nm, a[2]);
  a[3] = fmaf(b2f((unsigned short)(v.y >> 16)),     nm, a[3]);
  a[4] = fmaf(b2f((unsigned short)(v.z & 0xffffu)), nm, a[4]);
  a[5] = fmaf(b2f((unsigned short)(v.z >> 16)),     nm, a[5]);
  a[6] = fmaf(b2f((unsigned short)(v.w & 0xffffu)), nm, a[6]);
  a[7] = fmaf(b2f((unsigned short)(v.w >> 16)),     nm, a[7]);
}

template <bool RELU>
__global__ __launch_bounds__(256)
void gather_agg(const unsigned short* __restrict__ h, const float* __restrict__ dinv,
                const int* __restrict__ rowstart, const int* __restrict__ csr_src,
                const float* __restrict__ csr_norm, const float* __restrict__ bias,
                unsigned short* __restrict__ outb, int n)
{
  int node = blockIdx.x * 4 + (threadIdx.x >> 6);
  if (node >= n) return;
  const int lane = threadIdx.x & 63;
  const int c8 = lane * 8;

  float di = dinv[node];
  float slf = di * di;
  uint4 hv = *(const uint4*)&h[(size_t)node * 512 + c8];
  const float4* bp = (const float4*)&bias[c8];
  float4 b0 = bp[0], b1 = bp[1];
  float a[8] = {b0.x, b0.y, b0.z, b0.w, b1.x, b1.y, b1.z, b1.w};
  acc8(a, hv, slf);

  const int jb = rowstart[node], je = rowstart[node + 1];
  int j = jb;
  for (; j + 8 <= je; j += 8) {
    int ss[8]; float nrm[8]; uint4 vv[8];
    #pragma unroll
    for (int q = 0; q < 8; q++) { ss[q] = csr_src[j + q]; nrm[q] = csr_norm[j + q]; }
    #pragma unroll
    for (int q = 0; q < 8; q++) vv[q] = *(const uint4*)&h[(size_t)ss[q] * 512 + c8];
    #pragma unroll
    for (int q = 0; q < 8; q++) acc8(a, vv[q], nrm[q]);
  }
  for (; j + 4 <= je; j += 4) {
    int ss[4]; float nrm[4]; uint4 vv[4];
    #pragma unroll
    for (int q = 0; q < 4; q++) { ss[q] = csr_src[j + q]; nrm[q] = csr_norm[j + q]; }
    #pragma unroll
    for (int q = 0; q < 4; q++) vv[q] = *(const uint4*)&h[(size_t)ss[q] * 512 + c8];
    #pragma unroll
    for (int q = 0; q < 4; q++) acc8(a, vv[q], nrm[q]);
  }
  for (; j < je; ++j) {
    uint4 v = *(const uint4*)&h[(size_t)csr_src[j] * 512 + c8];
    acc8(a, v, csr_norm[j]);
  }
  if (RELU) {
    #pragma unroll
    for (int q = 0; q < 8; q++) a[q] = fmaxf(a[q], 0.f);
  }
  uint4 o;
  o.x = (unsigned int)f2b(a[0]) | ((unsigned int)f2b(a[1]) << 16);
  o.y = (unsigned int)f2b(a[2]) | ((unsigned int)f2b(a[3]) << 16);
  o.z = (unsigned int)f2b(a[4]) | ((unsigned int)f2b(a[5]) << 16);
  o.w = (unsigned int)f2b(a[6]) | ((unsigned int)f2b(a[7]) << 16);
  *(uint4*)&outb[(size_t)node * 512 + c8] = o;
}

extern "C" void kernel_launch(void* const* d_in, const int* in_sizes, int n_in,
                              void* d_out, int out_size, void* d_ws, size_t ws_size,
                              hipStream_t stream) {
  const float* x  = (const float*)d_in[0];
  const int*   ei = (const int*)d_in[1];
  const float* W1 = (const float*)d_in[2];
  const float* b1 = (const float*)d_in[3];
  const float* W2 = (const float*)d_in[4];
  const float* b2 = (const float*)d_in[5];
  const float* Wc = (const float*)d_in[6];
  const float* bc = (const float*)d_in[7];
  float* out = (float*)d_out;

  const int n = NN;
  const int E = in_sizes[1] / 2;
  const int* src = ei;
  const int* dst = ei + E;

  // workspace (~33 MB)
  char* w = (char*)d_ws;
  float* dinv = (float*)w;                  w += ((n * 4 + 255) / 256) * 256;
  int* edeg = (int*)w;                      w += ((n * 4 + 255) / 256) * 256;   // also fill cursor
  int* rowstart = (int*)w;                  w += (((n + 1) * 4 + 255) / 256) * 256;
  int* csr_src = (int*)w;                   w += ((E * 4 + 255) / 256) * 256;
  float* csr_norm = (float*)w;              w += ((E * 4 + 255) / 256) * 256;
  unsigned short* xb  = (unsigned short*)w; w += (size_t)n * 512 * 2;
  unsigned short* W1t = (unsigned short*)w; w += 512 * 512 * 2;
  unsigned short* W2t = (unsigned short*)w; w += 512 * 512 * 2;
  unsigned short* Wct = (unsigned short*)w; w += 128 * 512 * 2;
  unsigned short* B1  = (unsigned short*)w; w += (size_t)n * 512 * 2;  // agg out / next A
  unsigned short* B2  = (unsigned short*)w; w += (size_t)n * 512 * 2;  // h (pre-agg)

  const int nb_e = (E + 255) / 256;
  const int prep_items = n * 512 + E;
  const int nb_prep = (prep_items + 255) / 256;
  dim3 gw(8, 8, 3);
  dim3 g1((n + 127) / 128, 4);
  dim3 g3((n + 127) / 128, 1);
  const int nb_g = (n + 3) / 4;

  hipMemsetAsync(edeg, 0, n * sizeof(int), stream);
  prep<<<nb_prep, 256, 0, stream>>>(x, dst, edeg, xb, E);
  wtrans<<<gw, 256, 0, stream>>>(W1, W2, Wc, W1t, W2t, Wct);
  csr_scan<<<1, 256, 0, stream>>>(edeg, rowstart, dinv, n);
  csr_fill<<<nb_e, 256, 0, stream>>>(src, dst, dinv, rowstart, edeg, csr_src, csr_norm, E);

  // layer 1
  gemm_bb<false, true><<<g1, 256, 0, stream>>>(xb, W1t, B2, nullptr, n, 512, 512);
  gather_agg<true><<<nb_g, 256, 0, stream>>>(B2, dinv, rowstart, csr_src, csr_norm, b1, B1, n);

  // layer 2
  gemm_bb<false, true><<<g1, 256, 0, stream>>>(B1, W2t, B2, nullptr, n, 512, 512);
  gather_agg<false><<<nb_g, 256, 0, stream>>>(B2, dinv, rowstart, csr_src, csr_norm, b2, B1, n);

  // classifier (fp32 out)
  gemm_bb<true, false><<<g3, 256, 0, stream>>>(B1, Wct, out, bc, n, 100, 100);
}